// Round 1
// baseline (131.948 us; speedup 1.0000x reference)
//
#include <hip/hip_runtime.h>
#include <hip/hip_bf16.h>
#include <stdint.h>

#define B_  4
#define L_  1024
#define C_  512
#define H_  8
#define D_  64
#define BH_ 32
#define M_  4096

typedef short  bf16x8 __attribute__((ext_vector_type(8)));
typedef float  f32x4  __attribute__((ext_vector_type(4)));

__device__ __forceinline__ unsigned short f2bf(float f) {
    union { float f; uint32_t u; } v; v.f = f;
    uint32_t u = v.u;
    return (unsigned short)((u + 0x7fffu + ((u >> 16) & 1u)) >> 16);
}
__device__ __forceinline__ float bf2f(unsigned short s) {
    union { uint32_t u; float f; } v; v.u = ((uint32_t)s) << 16;
    return v.f;
}

// ---------------- f32 -> bf16 convert ----------------
__global__ void cvt_bf16(const float* __restrict__ in, unsigned short* __restrict__ out, int n4) {
    int i = blockIdx.x * blockDim.x + threadIdx.x;
    if (i < n4) {
        float4 v = ((const float4*)in)[i];
        ushort4 o;
        o.x = f2bf(v.x); o.y = f2bf(v.y); o.z = f2bf(v.z); o.w = f2bf(v.w);
        ((ushort4*)out)[i] = o;
    }
}

// ---------------- precompute Ef = exp(bs0*adj_local), Eb = exp(bs1*adj_local^T) ----------------
__global__ __launch_bounds__(256) void prep_e(const float* __restrict__ adj,
                                              const float* __restrict__ bias_scale,
                                              unsigned short* __restrict__ Ef,
                                              unsigned short* __restrict__ Eb) {
    __shared__ float Tr[64][65];
    const int b = blockIdx.z, q0 = blockIdx.y * 64, k0 = blockIdx.x * 64;
    const float* adjb = adj + (size_t)b * L_ * L_;
    const int tid = threadIdx.x;
#pragma unroll
    for (int i = 0; i < 4; ++i) {
        int idx = i * 256 + tid;                 // 0..1023
        int rk = idx >> 4, c4 = (idx & 15) * 4;  // row (k), col4 (q)
        const float* src = adjb + (size_t)(k0 + rk) * L_ + q0 + c4;
        float4 v = *(const float4*)src;
        Tr[rk][c4 + 0] = v.x; Tr[rk][c4 + 1] = v.y; Tr[rk][c4 + 2] = v.z; Tr[rk][c4 + 3] = v.w;
    }
    __syncthreads();
    const float bs0 = bias_scale[0], bs1 = bias_scale[1];
#pragma unroll
    for (int i = 0; i < 16; ++i) {
        int idx = i * 256 + tid;                 // 0..4095
        int ql = idx >> 6, kl = idx & 63;
        int qg = q0 + ql, kg = k0 + kl;
        float af = adjb[(size_t)qg * L_ + kg];
        float ab = Tr[kl][ql];                   // adj[b][kg][qg]
        bool z = (qg == 0) || (kg == 0);
        float ef = z ? 1.0f : __expf(bs0 * af);
        float eb = z ? 1.0f : __expf(bs1 * ab);
        size_t o = (size_t)b * L_ * L_ + (size_t)qg * L_ + kg;
        Ef[o] = f2bf(ef);
        Eb[o] = f2bf(eb);
    }
}

// ---------------- bf16 MFMA GEMM: out[M,N] = A[M,K] * B[N,K]^T ----------------
// EPI 0: scatter qkv -> Qb/Kb (bf16 [bh][l][d]) and Vt (bf16 [bh][d][l])
// EPI 1: f32 store to out[M,N]
template <int KDIM, int NDIM, int EPI>
__global__ __launch_bounds__(256, 2) void gemm_bf16(const unsigned short* __restrict__ Amat,
                                                    const unsigned short* __restrict__ Bmat,
                                                    float* __restrict__ outp,
                                                    unsigned short* __restrict__ q_out,
                                                    unsigned short* __restrict__ k_out,
                                                    unsigned short* __restrict__ v_out) {
    __shared__ __align__(16) unsigned short As[128 * 64];
    __shared__ __align__(16) unsigned short Bs[128 * 64];
    const int tid = threadIdx.x;
    const int l = tid & 63, wid = tid >> 6;
    const int g = l >> 4, c = l & 15;
    const int wr = wid >> 1, wc = wid & 1;
    const int row0 = blockIdx.y * 128, col0 = blockIdx.x * 128;

    f32x4 acc[4][4];
#pragma unroll
    for (int mi = 0; mi < 4; ++mi)
#pragma unroll
        for (int ni = 0; ni < 4; ++ni) acc[mi][ni] = (f32x4){0.f, 0.f, 0.f, 0.f};

    for (int k0 = 0; k0 < KDIM; k0 += 64) {
        bf16x8 ra[4], rb[4];
#pragma unroll
        for (int i = 0; i < 4; ++i) {
            int q = i * 256 + tid;              // 16B-chunk index 0..1023
            int r = q >> 3, cb = (q & 7) * 16;  // row, byte-in-row
            ra[i] = *(const bf16x8*)((const char*)Amat + (size_t)(row0 + r) * (KDIM * 2) + k0 * 2 + cb);
            rb[i] = *(const bf16x8*)((const char*)Bmat + (size_t)(col0 + r) * (KDIM * 2) + k0 * 2 + cb);
        }
        __syncthreads();   // previous iteration's readers are done
#pragma unroll
        for (int i = 0; i < 4; ++i) {
            int q = i * 256 + tid;
            int r = q >> 3, cb = (q & 7) * 16;
            int sw = cb ^ ((r & 7) << 4);
            *(bf16x8*)((char*)As + r * 128 + sw) = ra[i];
            *(bf16x8*)((char*)Bs + r * 128 + sw) = rb[i];
        }
        __syncthreads();
#pragma unroll
        for (int kk = 0; kk < 2; ++kk) {
            bf16x8 afr[4], bfr[4];
#pragma unroll
            for (int mi = 0; mi < 4; ++mi) {
                int r = wr * 64 + mi * 16 + c;
                afr[mi] = *(const bf16x8*)((const char*)As + r * 128 + ((kk * 64 + g * 16) ^ ((r & 7) << 4)));
            }
#pragma unroll
            for (int ni = 0; ni < 4; ++ni) {
                int r = wc * 64 + ni * 16 + c;
                bfr[ni] = *(const bf16x8*)((const char*)Bs + r * 128 + ((kk * 64 + g * 16) ^ ((r & 7) << 4)));
            }
#pragma unroll
            for (int mi = 0; mi < 4; ++mi)
#pragma unroll
                for (int ni = 0; ni < 4; ++ni)
                    acc[mi][ni] = __builtin_amdgcn_mfma_f32_16x16x32_bf16(afr[mi], bfr[ni], acc[mi][ni], 0, 0, 0);
        }
    }
    // epilogue
#pragma unroll
    for (int mi = 0; mi < 4; ++mi) {
#pragma unroll
        for (int ni = 0; ni < 4; ++ni) {
#pragma unroll
            for (int ii = 0; ii < 4; ++ii) {
                int m = row0 + wr * 64 + mi * 16 + g * 4 + ii;
                int n = col0 + wc * 64 + ni * 16 + c;
                float val = acc[mi][ni][ii];
                if (EPI == 0) {
                    unsigned short v = f2bf(val);
                    int b = m >> 10, ll = m & 1023;
                    int which = n >> 9, cc = n & 511;
                    int hh = cc >> 6, d = cc & 63;
                    int bh = b * 8 + hh;
                    if (which == 0)      q_out[((size_t)bh * L_ + ll) * D_ + d] = v;
                    else if (which == 1) k_out[((size_t)bh * L_ + ll) * D_ + d] = v;
                    else                 v_out[((size_t)bh * D_ + d) * L_ + ll] = v;
                } else {
                    outp[(size_t)m * NDIM + n] = val;
                }
            }
        }
    }
}

// ---------------- fused 3-branch attention ----------------
// grid: (L/64, BH). 4 independent waves/block, each owns 16 q-rows. No barriers.
__global__ __launch_bounds__(256, 2) void attn_kernel(const unsigned short* __restrict__ Qb,
                                                      const unsigned short* __restrict__ Kb,
                                                      const unsigned short* __restrict__ Vtb,
                                                      const unsigned short* __restrict__ Ef,
                                                      const unsigned short* __restrict__ Eb,
                                                      const float* __restrict__ beta,
                                                      unsigned short* __restrict__ hb) {
    __shared__ __align__(16) unsigned short P_lds[4][3][1024];  // per wave: [q16][k64] bf16, XOR-swizzled
    const int tid = threadIdx.x;
    const int w = tid >> 6, l = tid & 63;
    const int g = l >> 4, c = l & 15;
    const int bh = blockIdx.y, b = bh >> 3;
    const int q0 = blockIdx.x * 64 + w * 16;  // wave's q base within L

    // Q fragments held in registers for the whole loop
    const unsigned short* Qrow = Qb + ((size_t)bh * L_ + q0 + c) * D_;
    const bf16x8 qf0 = *(const bf16x8*)(Qrow + g * 8);
    const bf16x8 qf1 = *(const bf16x8*)(Qrow + 32 + g * 8);

    f32x4 O[3][4];
    float lsum[3][4];
#pragma unroll
    for (int j = 0; j < 3; ++j) {
#pragma unroll
        for (int dc = 0; dc < 4; ++dc) O[j][dc] = (f32x4){0.f, 0.f, 0.f, 0.f};
#pragma unroll
        for (int i = 0; i < 4; ++i) lsum[j][i] = 0.f;
    }

    const unsigned short* Kbase = Kb + (size_t)bh * L_ * D_;
    const unsigned short* Vbase = Vtb + (size_t)bh * D_ * L_;
    const unsigned short* Efb = Ef + (size_t)b * L_ * L_;
    const unsigned short* Ebb = Eb + (size_t)b * L_ * L_;

    for (int k0 = 0; k0 < L_; k0 += 64) {
        // ---- S phase: 4 sub-tiles of 16 k-columns ----
#pragma unroll
        for (int ks = 0; ks < 4; ++ks) {
            const int kbase = k0 + ks * 16;
            const unsigned short* Krow = Kbase + (size_t)(kbase + c) * D_;
            bf16x8 kf0 = *(const bf16x8*)(Krow + g * 8);
            bf16x8 kf1 = *(const bf16x8*)(Krow + 32 + g * 8);
            f32x4 s = (f32x4){0.f, 0.f, 0.f, 0.f};
            s = __builtin_amdgcn_mfma_f32_16x16x32_bf16(qf0, kf0, s, 0, 0, 0);
            s = __builtin_amdgcn_mfma_f32_16x16x32_bf16(qf1, kf1, s, 0, 0, 0);
            const int kcol = kbase + c;
#pragma unroll
            for (int i = 0; i < 4; ++i) {
                int qrow = q0 + g * 4 + i;
                float p0 = __expf(s[i] * 0.125f);
                float p1 = p0 * bf2f(Efb[(size_t)qrow * L_ + kcol]);
                float p2 = p0 * bf2f(Ebb[(size_t)qrow * L_ + kcol]);
                lsum[0][i] += p0; lsum[1][i] += p1; lsum[2][i] += p2;
                int prow = g * 4 + i;
                int pcol = ks * 16 + c;
                int off = prow * 128 + ((pcol * 2) ^ ((prow & 7) << 4));
                *(unsigned short*)((char*)P_lds[w][0] + off) = f2bf(p0);
                *(unsigned short*)((char*)P_lds[w][1] + off) = f2bf(p1);
                *(unsigned short*)((char*)P_lds[w][2] + off) = f2bf(p2);
            }
        }
        // ---- PV phase ----
#pragma unroll
        for (int kk = 0; kk < 2; ++kk) {
            bf16x8 vf[4];
#pragma unroll
            for (int dc = 0; dc < 4; ++dc) {
                int drow = dc * 16 + c;
                vf[dc] = *(const bf16x8*)(Vbase + (size_t)drow * L_ + k0 + kk * 32 + g * 8);
            }
#pragma unroll
            for (int j = 0; j < 3; ++j) {
                int r = c;
                bf16x8 af = *(const bf16x8*)((char*)P_lds[w][j] + r * 128 + ((kk * 64 + g * 16) ^ ((r & 7) << 4)));
#pragma unroll
                for (int dc = 0; dc < 4; ++dc)
                    O[j][dc] = __builtin_amdgcn_mfma_f32_16x16x32_bf16(af, vf[dc], O[j][dc], 0, 0, 0);
            }
        }
    }

    // reduce row sums over the 16 lanes sharing a row group
#pragma unroll
    for (int j = 0; j < 3; ++j)
#pragma unroll
        for (int i = 0; i < 4; ++i) {
            float v = lsum[j][i];
            v += __shfl_xor(v, 1);
            v += __shfl_xor(v, 2);
            v += __shfl_xor(v, 4);
            v += __shfl_xor(v, 8);
            lsum[j][i] = v;
        }

    // softmax(beta) branch weights
    float b0 = beta[0], b1 = beta[1], b2 = beta[2];
    float bm = fmaxf(b0, fmaxf(b1, b2));
    float e0 = __expf(b0 - bm), e1 = __expf(b1 - bm), e2 = __expf(b2 - bm);
    float inv = 1.0f / (e0 + e1 + e2);
    float w0 = e0 * inv, w1 = e1 * inv, w2 = e2 * inv;

    const int hcolbase = (bh & 7) * 64;
#pragma unroll
    for (int dc = 0; dc < 4; ++dc) {
#pragma unroll
        for (int i = 0; i < 4; ++i) {
            float h = w0 * O[0][dc][i] / lsum[0][i]
                    + w1 * O[1][dc][i] / lsum[1][i]
                    + w2 * O[2][dc][i] / lsum[2][i];
            int qrow = q0 + g * 4 + i;
            int d = dc * 16 + c;
            hb[(size_t)((b << 10) + qrow) * C_ + hcolbase + d] = f2bf(h);
        }
    }
}

extern "C" void kernel_launch(void* const* d_in, const int* in_sizes, int n_in,
                              void* d_out, int out_size, void* d_ws, size_t ws_size,
                              hipStream_t stream) {
    const float* x          = (const float*)d_in[0];
    const float* adj        = (const float*)d_in[1];
    const float* wqkv       = (const float*)d_in[2];
    const float* wproj      = (const float*)d_in[3];
    const float* bias_scale = (const float*)d_in[4];
    const float* beta       = (const float*)d_in[5];
    float* out = (float*)d_out;

    char* ws = (char*)d_ws;
    size_t off = 0;
    auto alloc = [&](size_t bytes) {
        void* p = ws + off;
        off += (bytes + 255) & ~(size_t)255;
        return p;
    };
    unsigned short* xb     = (unsigned short*)alloc((size_t)M_ * C_ * 2);
    unsigned short* wqkvb  = (unsigned short*)alloc((size_t)3 * C_ * C_ * 2);
    unsigned short* wprojb = (unsigned short*)alloc((size_t)C_ * C_ * 2);
    unsigned short* Qb     = (unsigned short*)alloc((size_t)BH_ * L_ * D_ * 2);
    unsigned short* Kb     = (unsigned short*)alloc((size_t)BH_ * L_ * D_ * 2);
    unsigned short* Vtb    = (unsigned short*)alloc((size_t)BH_ * D_ * L_ * 2);
    unsigned short* Ef     = (unsigned short*)alloc((size_t)B_ * L_ * L_ * 2);
    unsigned short* Eb     = (unsigned short*)alloc((size_t)B_ * L_ * L_ * 2);
    unsigned short* hb     = (unsigned short*)alloc((size_t)M_ * C_ * 2);

    {
        int n4 = M_ * C_ / 4;
        cvt_bf16<<<(n4 + 255) / 256, 256, 0, stream>>>(x, xb, n4);
    }
    {
        int n4 = 3 * C_ * C_ / 4;
        cvt_bf16<<<(n4 + 255) / 256, 256, 0, stream>>>(wqkv, wqkvb, n4);
    }
    {
        int n4 = C_ * C_ / 4;
        cvt_bf16<<<(n4 + 255) / 256, 256, 0, stream>>>(wproj, wprojb, n4);
    }
    prep_e<<<dim3(L_ / 64, L_ / 64, B_), 256, 0, stream>>>(adj, bias_scale, Ef, Eb);
    gemm_bf16<512, 1536, 0><<<dim3(1536 / 128, M_ / 128), 256, 0, stream>>>(xb, wqkvb, nullptr, Qb, Kb, Vtb);
    attn_kernel<<<dim3(L_ / 64, BH_), 256, 0, stream>>>(Qb, Kb, Vtb, Ef, Eb, beta, hb);
    gemm_bf16<512, 512, 1><<<dim3(512 / 128, M_ / 128), 256, 0, stream>>>(hb, wprojb, out, nullptr, nullptr, nullptr);
}

// Round 3
// 125.428 us; speedup vs baseline: 1.0520x; 1.0520x over previous
//
#include <hip/hip_runtime.h>
#include <hip/hip_bf16.h>
#include <stdint.h>

#define B_  4
#define L_  1024
#define C_  512
#define H_  8
#define D_  64
#define BH_ 32
#define M_  4096

typedef short  bf16x8 __attribute__((ext_vector_type(8)));
typedef short  bf16x4 __attribute__((ext_vector_type(4)));
typedef float  f32x4  __attribute__((ext_vector_type(4)));

__device__ __forceinline__ unsigned short f2bf(float f) {
    union { float f; uint32_t u; } v; v.f = f;
    uint32_t u = v.u;
    return (unsigned short)((u + 0x7fffu + ((u >> 16) & 1u)) >> 16);
}
__device__ __forceinline__ float bf2f(unsigned short s) {
    union { uint32_t u; float f; } v; v.u = ((uint32_t)s) << 16;
    return v.f;
}

// ---------------- f32 -> bf16 convert ----------------
__global__ void cvt_bf16(const float* __restrict__ in, unsigned short* __restrict__ out, int n4) {
    int i = blockIdx.x * blockDim.x + threadIdx.x;
    if (i < n4) {
        float4 v = ((const float4*)in)[i];
        ushort4 o;
        o.x = f2bf(v.x); o.y = f2bf(v.y); o.z = f2bf(v.z); o.w = f2bf(v.w);
        ((ushort4*)out)[i] = o;
    }
}

// ---------------- precompute E = exp(bias) in MFMA fragment layout ----------------
// EF/EB layout: [b][q16(64)][k16(64)][lane(64)][4] bf16, where element i of lane l
// corresponds to S-tile accumulator reg i: q = q16*16 + (l>>4)*4 + i, k = k16*16 + (l&15).
__global__ __launch_bounds__(256) void prep_e(const float* __restrict__ adj,
                                              const float* __restrict__ bias_scale,
                                              unsigned short* __restrict__ EF,
                                              unsigned short* __restrict__ EB) {
    __shared__ float Tr[64][65];
    const int b = blockIdx.z, q0 = blockIdx.y * 64, k0 = blockIdx.x * 64;
    const float* adjb = adj + (size_t)b * L_ * L_;
    const int tid = threadIdx.x;
#pragma unroll
    for (int i = 0; i < 4; ++i) {
        int idx = i * 256 + tid;                 // 0..1023
        int rk = idx >> 4, c4 = (idx & 15) * 4;  // row (k), col4 (q)
        const float* src = adjb + (size_t)(k0 + rk) * L_ + q0 + c4;
        float4 v = *(const float4*)src;
        Tr[rk][c4 + 0] = v.x; Tr[rk][c4 + 1] = v.y; Tr[rk][c4 + 2] = v.z; Tr[rk][c4 + 3] = v.w;
    }
    __syncthreads();
    const float bs0 = bias_scale[0], bs1 = bias_scale[1];
    const int w = tid >> 6, l = tid & 63, g = l >> 4, c = l & 15;
#pragma unroll
    for (int kt = 0; kt < 4; ++kt) {
        ushort4 efv, ebv;
#pragma unroll
        for (int i = 0; i < 4; ++i) {
            int ql = w * 16 + g * 4 + i, kl = kt * 16 + c;
            int qg = q0 + ql, kg = k0 + kl;
            float af = adjb[(size_t)qg * L_ + kg];
            float ab = Tr[kl][ql];               // adj[b][kg][qg]
            bool z = (qg == 0) || (kg == 0);
            float ef = z ? 1.0f : __expf(bs0 * af);
            float eb = z ? 1.0f : __expf(bs1 * ab);
            ((unsigned short*)&efv)[i] = f2bf(ef);
            ((unsigned short*)&ebv)[i] = f2bf(eb);
        }
        size_t fo = (((size_t)b * 64 + (blockIdx.y * 4 + w)) * 64 + (blockIdx.x * 4 + kt)) * 256 + (size_t)l * 4;
        *(ushort4*)(EF + fo) = efv;
        *(ushort4*)(EB + fo) = ebv;
    }
}

// ---------------- bf16 MFMA GEMM: out[M,N] = A[M,K] * B[N,K]^T ----------------
template <int KDIM, int NDIM, int EPI>
__global__ __launch_bounds__(256, 2) void gemm_bf16(const unsigned short* __restrict__ Amat,
                                                    const unsigned short* __restrict__ Bmat,
                                                    float* __restrict__ outp,
                                                    unsigned short* __restrict__ q_out,
                                                    unsigned short* __restrict__ k_out,
                                                    unsigned short* __restrict__ v_out) {
    __shared__ __align__(16) unsigned short As[128 * 64];
    __shared__ __align__(16) unsigned short Bs[128 * 64];
    const int tid = threadIdx.x;
    const int l = tid & 63, wid = tid >> 6;
    const int g = l >> 4, c = l & 15;
    const int wr = wid >> 1, wc = wid & 1;
    const int row0 = blockIdx.y * 128, col0 = blockIdx.x * 128;

    f32x4 acc[4][4];
#pragma unroll
    for (int mi = 0; mi < 4; ++mi)
#pragma unroll
        for (int ni = 0; ni < 4; ++ni) acc[mi][ni] = (f32x4){0.f, 0.f, 0.f, 0.f};

    for (int k0 = 0; k0 < KDIM; k0 += 64) {
        bf16x8 ra[4], rb[4];
#pragma unroll
        for (int i = 0; i < 4; ++i) {
            int q = i * 256 + tid;
            int r = q >> 3, cb = (q & 7) * 16;
            ra[i] = *(const bf16x8*)((const char*)Amat + (size_t)(row0 + r) * (KDIM * 2) + k0 * 2 + cb);
            rb[i] = *(const bf16x8*)((const char*)Bmat + (size_t)(col0 + r) * (KDIM * 2) + k0 * 2 + cb);
        }
        __syncthreads();
#pragma unroll
        for (int i = 0; i < 4; ++i) {
            int q = i * 256 + tid;
            int r = q >> 3, cb = (q & 7) * 16;
            int sw = cb ^ ((r & 7) << 4);
            *(bf16x8*)((char*)As + r * 128 + sw) = ra[i];
            *(bf16x8*)((char*)Bs + r * 128 + sw) = rb[i];
        }
        __syncthreads();
#pragma unroll
        for (int kk = 0; kk < 2; ++kk) {
            bf16x8 afr[4], bfr[4];
#pragma unroll
            for (int mi = 0; mi < 4; ++mi) {
                int r = wr * 64 + mi * 16 + c;
                afr[mi] = *(const bf16x8*)((const char*)As + r * 128 + ((kk * 64 + g * 16) ^ ((r & 7) << 4)));
            }
#pragma unroll
            for (int ni = 0; ni < 4; ++ni) {
                int r = wc * 64 + ni * 16 + c;
                bfr[ni] = *(const bf16x8*)((const char*)Bs + r * 128 + ((kk * 64 + g * 16) ^ ((r & 7) << 4)));
            }
#pragma unroll
            for (int mi = 0; mi < 4; ++mi)
#pragma unroll
                for (int ni = 0; ni < 4; ++ni)
                    acc[mi][ni] = __builtin_amdgcn_mfma_f32_16x16x32_bf16(afr[mi], bfr[ni], acc[mi][ni], 0, 0, 0);
        }
    }
#pragma unroll
    for (int mi = 0; mi < 4; ++mi) {
#pragma unroll
        for (int ni = 0; ni < 4; ++ni) {
#pragma unroll
            for (int ii = 0; ii < 4; ++ii) {
                int m = row0 + wr * 64 + mi * 16 + g * 4 + ii;
                int n = col0 + wc * 64 + ni * 16 + c;
                float val = acc[mi][ni][ii];
                if (EPI == 0) {
                    unsigned short v = f2bf(val);
                    int b = m >> 10, ll = m & 1023;
                    int which = n >> 9, cc = n & 511;
                    int hh = cc >> 6, d = cc & 63;
                    int bh = b * 8 + hh;
                    if (which == 0)      q_out[((size_t)bh * L_ + ll) * D_ + d] = v;
                    else if (which == 1) k_out[((size_t)bh * L_ + ll) * D_ + d] = v;
                    else                 v_out[((size_t)bh * D_ + d) * L_ + ll] = v;
                } else {
                    outp[(size_t)m * NDIM + n] = val;
                }
            }
        }
    }
}

// ---------------- fused 3-branch attention (pipelined, ping-pong P LDS) ----------------
struct KERegs {
    bf16x8 kf0[4], kf1[4];
    bf16x4 ef[4], eb[4];
};

__device__ __forceinline__ void load_tile(KERegs& X, int t,
                                          const unsigned short* __restrict__ Kbase,
                                          const unsigned short* __restrict__ efp,
                                          const unsigned short* __restrict__ ebp,
                                          int c, int g, int l) {
    const int k0 = t * 64;
#pragma unroll
    for (int ks = 0; ks < 4; ++ks) {
        const unsigned short* Krow = Kbase + (size_t)(k0 + ks * 16 + c) * D_;
        X.kf0[ks] = *(const bf16x8*)(Krow + g * 8);
        X.kf1[ks] = *(const bf16x8*)(Krow + 32 + g * 8);
        size_t eo = (size_t)(4 * t + ks) * 256 + (size_t)l * 4;
        X.ef[ks] = *(const bf16x4*)(efp + eo);
        X.eb[ks] = *(const bf16x4*)(ebp + eo);
    }
}

__device__ __forceinline__ void compute_tile(const KERegs& X, int t,
                                             const unsigned short* __restrict__ Vbase,
                                             char* pb0, char* pb1, char* pb2,
                                             bf16x8 qf0, bf16x8 qf1,
                                             f32x4 (&O)[3][4], float (&lsum)[3][4],
                                             int c, int g) {
    const int k0 = t * 64;
    bf16x8 vf[2][4];
#pragma unroll
    for (int kk = 0; kk < 2; ++kk)
#pragma unroll
        for (int dc = 0; dc < 4; ++dc)
            vf[kk][dc] = *(const bf16x8*)(Vbase + (size_t)(dc * 16 + c) * L_ + k0 + kk * 32 + g * 8);

#pragma unroll
    for (int ks = 0; ks < 4; ++ks) {
        f32x4 s = (f32x4){0.f, 0.f, 0.f, 0.f};
        s = __builtin_amdgcn_mfma_f32_16x16x32_bf16(qf0, X.kf0[ks], s, 0, 0, 0);
        s = __builtin_amdgcn_mfma_f32_16x16x32_bf16(qf1, X.kf1[ks], s, 0, 0, 0);
#pragma unroll
        for (int i = 0; i < 4; ++i) {
            float p0 = __expf(s[i] * 0.125f);
            float p1 = p0 * bf2f((unsigned short)X.ef[ks][i]);
            float p2 = p0 * bf2f((unsigned short)X.eb[ks][i]);
            lsum[0][i] += p0; lsum[1][i] += p1; lsum[2][i] += p2;
            int prow = g * 4 + i;
            int off = prow * 128 + ((((ks * 16 + c) * 2)) ^ ((prow & 7) << 4));
            *(unsigned short*)(pb0 + off) = f2bf(p0);
            *(unsigned short*)(pb1 + off) = f2bf(p1);
            *(unsigned short*)(pb2 + off) = f2bf(p2);
        }
    }
#pragma unroll
    for (int kk = 0; kk < 2; ++kk) {
#pragma unroll
        for (int j = 0; j < 3; ++j) {
            char* pb = (j == 0) ? pb0 : ((j == 1) ? pb1 : pb2);
            bf16x8 af = *(const bf16x8*)(pb + c * 128 + ((kk * 64 + g * 16) ^ ((c & 7) << 4)));
#pragma unroll
            for (int dc = 0; dc < 4; ++dc)
                O[j][dc] = __builtin_amdgcn_mfma_f32_16x16x32_bf16(af, vf[kk][dc], O[j][dc], 0, 0, 0);
        }
    }
}

__global__ __launch_bounds__(256, 2) void attn_kernel(const unsigned short* __restrict__ Qb,
                                                      const unsigned short* __restrict__ Kb,
                                                      const unsigned short* __restrict__ Vtb,
                                                      const unsigned short* __restrict__ EF,
                                                      const unsigned short* __restrict__ EB,
                                                      const float* __restrict__ beta,
                                                      unsigned short* __restrict__ hb) {
    // ping-pong parity buffer: tile t uses parity t&1 -> writes of tile t+1 can
    // never touch bytes still being read by tile t's PV phase.
    __shared__ __align__(16) unsigned short P_lds[2][4][3][1024];
    const int tid = threadIdx.x;
    const int w = tid >> 6, l = tid & 63;
    const int g = l >> 4, c = l & 15;
    const int bh = blockIdx.y, b = bh >> 3;
    const int q0 = blockIdx.x * 64 + w * 16;
    const int qt = blockIdx.x * 4 + w;

    const unsigned short* Qrow = Qb + ((size_t)bh * L_ + q0 + c) * D_;
    const bf16x8 qf0 = *(const bf16x8*)(Qrow + g * 8);
    const bf16x8 qf1 = *(const bf16x8*)(Qrow + 32 + g * 8);

    f32x4 O[3][4];
    float lsum[3][4];
#pragma unroll
    for (int j = 0; j < 3; ++j) {
#pragma unroll
        for (int dc = 0; dc < 4; ++dc) O[j][dc] = (f32x4){0.f, 0.f, 0.f, 0.f};
#pragma unroll
        for (int i = 0; i < 4; ++i) lsum[j][i] = 0.f;
    }

    const unsigned short* Kbase = Kb + (size_t)bh * L_ * D_;
    const unsigned short* Vbase = Vtb + (size_t)bh * D_ * L_;
    const unsigned short* efp = EF + ((size_t)(b * 64 + qt) * 64) * 256;
    const unsigned short* ebp = EB + ((size_t)(b * 64 + qt) * 64) * 256;
    char* pa0 = (char*)P_lds[0][w][0];
    char* pa1 = (char*)P_lds[0][w][1];
    char* pa2 = (char*)P_lds[0][w][2];
    char* pc0 = (char*)P_lds[1][w][0];
    char* pc1 = (char*)P_lds[1][w][1];
    char* pc2 = (char*)P_lds[1][w][2];

    KERegs RA, RB;
    load_tile(RA, 0, Kbase, efp, ebp, c, g, l);

    for (int t = 0; t < 16; t += 2) {
        load_tile(RB, t + 1, Kbase, efp, ebp, c, g, l);
        compute_tile(RA, t, Vbase, pa0, pa1, pa2, qf0, qf1, O, lsum, c, g);
        if (t + 2 < 16) load_tile(RA, t + 2, Kbase, efp, ebp, c, g, l);
        compute_tile(RB, t + 1, Vbase, pc0, pc1, pc2, qf0, qf1, O, lsum, c, g);
    }

#pragma unroll
    for (int j = 0; j < 3; ++j)
#pragma unroll
        for (int i = 0; i < 4; ++i) {
            float v = lsum[j][i];
            v += __shfl_xor(v, 1);
            v += __shfl_xor(v, 2);
            v += __shfl_xor(v, 4);
            v += __shfl_xor(v, 8);
            lsum[j][i] = v;
        }

    float b0 = beta[0], b1 = beta[1], b2 = beta[2];
    float bm = fmaxf(b0, fmaxf(b1, b2));
    float e0 = __expf(b0 - bm), e1 = __expf(b1 - bm), e2 = __expf(b2 - bm);
    float inv = 1.0f / (e0 + e1 + e2);
    float w0 = e0 * inv, w1 = e1 * inv, w2 = e2 * inv;

    const int hcolbase = (bh & 7) * 64;
#pragma unroll
    for (int dc = 0; dc < 4; ++dc) {
#pragma unroll
        for (int i = 0; i < 4; ++i) {
            float h = w0 * O[0][dc][i] / lsum[0][i]
                    + w1 * O[1][dc][i] / lsum[1][i]
                    + w2 * O[2][dc][i] / lsum[2][i];
            int qrow = q0 + g * 4 + i;
            int d = dc * 16 + c;
            hb[(size_t)((b << 10) + qrow) * C_ + hcolbase + d] = f2bf(h);
        }
    }
}

extern "C" void kernel_launch(void* const* d_in, const int* in_sizes, int n_in,
                              void* d_out, int out_size, void* d_ws, size_t ws_size,
                              hipStream_t stream) {
    const float* x          = (const float*)d_in[0];
    const float* adj        = (const float*)d_in[1];
    const float* wqkv       = (const float*)d_in[2];
    const float* wproj      = (const float*)d_in[3];
    const float* bias_scale = (const float*)d_in[4];
    const float* beta       = (const float*)d_in[5];
    float* out = (float*)d_out;

    char* ws = (char*)d_ws;
    size_t off = 0;
    auto alloc = [&](size_t bytes) {
        void* p = ws + off;
        off += (bytes + 255) & ~(size_t)255;
        return p;
    };
    unsigned short* xb     = (unsigned short*)alloc((size_t)M_ * C_ * 2);
    unsigned short* wqkvb  = (unsigned short*)alloc((size_t)3 * C_ * C_ * 2);
    unsigned short* wprojb = (unsigned short*)alloc((size_t)C_ * C_ * 2);
    unsigned short* Qb     = (unsigned short*)alloc((size_t)BH_ * L_ * D_ * 2);
    unsigned short* Kb     = (unsigned short*)alloc((size_t)BH_ * L_ * D_ * 2);
    unsigned short* Vtb    = (unsigned short*)alloc((size_t)BH_ * D_ * L_ * 2);
    unsigned short* EF     = (unsigned short*)alloc((size_t)B_ * L_ * L_ * 2);
    unsigned short* EB     = (unsigned short*)alloc((size_t)B_ * L_ * L_ * 2);
    unsigned short* hb     = (unsigned short*)alloc((size_t)M_ * C_ * 2);

    {
        int n4 = M_ * C_ / 4;
        cvt_bf16<<<(n4 + 255) / 256, 256, 0, stream>>>(x, xb, n4);
    }
    {
        int n4 = 3 * C_ * C_ / 4;
        cvt_bf16<<<(n4 + 255) / 256, 256, 0, stream>>>(wqkv, wqkvb, n4);
    }
    {
        int n4 = C_ * C_ / 4;
        cvt_bf16<<<(n4 + 255) / 256, 256, 0, stream>>>(wproj, wprojb, n4);
    }
    prep_e<<<dim3(L_ / 64, L_ / 64, B_), 256, 0, stream>>>(adj, bias_scale, EF, EB);
    gemm_bf16<512, 1536, 0><<<dim3(1536 / 128, M_ / 128), 256, 0, stream>>>(xb, wqkvb, nullptr, Qb, Kb, Vtb);
    attn_kernel<<<dim3(L_ / 64, BH_), 256, 0, stream>>>(Qb, Kb, Vtb, EF, EB, beta, hb);
    gemm_bf16<512, 512, 1><<<dim3(512 / 128, M_ / 128), 256, 0, stream>>>(hb, wprojb, out, nullptr, nullptr, nullptr);
}

// Round 5
// 82.154 us; speedup vs baseline: 1.6061x; 1.5267x over previous
//
#include <hip/hip_runtime.h>
#include <hip/hip_bf16.h>
#include <stdint.h>

#define B_  4
#define L_  1024
#define C_  512
#define H_  8
#define D_  64
#define BH_ 32
#define M_  4096

typedef short  bf16x8 __attribute__((ext_vector_type(8)));
typedef float  f32x4  __attribute__((ext_vector_type(4)));
typedef unsigned short u16x8 __attribute__((ext_vector_type(8)));
typedef unsigned int   u32x2 __attribute__((ext_vector_type(2)));

__device__ __forceinline__ unsigned short f2bf(float f) {
    union { float f; uint32_t u; } v; v.f = f;
    uint32_t u = v.u;
    return (unsigned short)((u + 0x7fffu + ((u >> 16) & 1u)) >> 16);
}
__device__ __forceinline__ float bf2f(unsigned short s) {
    union { uint32_t u; float f; } v; v.u = ((uint32_t)s) << 16;
    return v.f;
}

// async global->LDS, 16B per lane; LDS dest = wave-uniform base + lane*16
__device__ __forceinline__ void gload16(const void* g, void* s) {
    __builtin_amdgcn_global_load_lds((const __attribute__((address_space(1))) void*)g,
                                     (__attribute__((address_space(3))) void*)s, 16, 0, 0);
}

// ---------------- f32 -> bf16 convert ----------------
__global__ void cvt_bf16(const float* __restrict__ in, unsigned short* __restrict__ out, int n4) {
    int i = blockIdx.x * blockDim.x + threadIdx.x;
    if (i < n4) {
        float4 v = ((const float4*)in)[i];
        ushort4 o;
        o.x = f2bf(v.x); o.y = f2bf(v.y); o.z = f2bf(v.z); o.w = f2bf(v.w);
        ((ushort4*)out)[i] = o;
    }
}

// ---------------- precompute E = exp(bias) in swapped-QK fragment layout ----------------
// EI layout: [b][q16(64)][k16(64)][lane(64)][ef x4 | eb x4] bf16 (16B per lane).
// lane l=(c,g), elem i: q = q16*16 + c, k = k16*16 + 4g + i.
__global__ __launch_bounds__(256) void prep_e(const float* __restrict__ adj,
                                              const float* __restrict__ bias_scale,
                                              unsigned short* __restrict__ EI) {
    __shared__ float Tr[64][65];
    const int b = blockIdx.z, q0 = blockIdx.y * 64, k0 = blockIdx.x * 64;
    const float* adjb = adj + (size_t)b * L_ * L_;
    const int tid = threadIdx.x;
#pragma unroll
    for (int i = 0; i < 4; ++i) {
        int idx = i * 256 + tid;                 // 0..1023
        int rk = idx >> 4, c4 = (idx & 15) * 4;  // row (k), col4 (q)
        float4 v = *(const float4*)(adjb + (size_t)(k0 + rk) * L_ + q0 + c4);
        Tr[rk][c4 + 0] = v.x; Tr[rk][c4 + 1] = v.y; Tr[rk][c4 + 2] = v.z; Tr[rk][c4 + 3] = v.w;
    }
    __syncthreads();
    const float bs0 = bias_scale[0], bs1 = bias_scale[1];
    const int w = tid >> 6, l = tid & 63, g = l >> 4, c = l & 15;
#pragma unroll
    for (int qs = 0; qs < 4; ++qs) {
        int ql = qs * 16 + c, qg = q0 + ql;
        int klb = w * 16 + g * 4;
        float4 af4 = *(const float4*)(adjb + (size_t)qg * L_ + k0 + klb);
        unsigned short ef[4], eb[4];
        const float afv[4] = {af4.x, af4.y, af4.z, af4.w};
#pragma unroll
        for (int i = 0; i < 4; ++i) {
            int kg = k0 + klb + i;
            bool z = (qg == 0) || (kg == 0);
            ef[i] = f2bf(z ? 1.0f : __expf(bs0 * afv[i]));
            eb[i] = f2bf(z ? 1.0f : __expf(bs1 * Tr[klb + i][ql]));
        }
        size_t o = (((size_t)b * 64 + (blockIdx.y * 4 + qs)) * 64 + (blockIdx.x * 4 + w)) * 512 + (size_t)l * 8;
        u16x8 o8 = {ef[0], ef[1], ef[2], ef[3], eb[0], eb[1], eb[2], eb[3]};
        *(u16x8*)(EI + o) = o8;
    }
}

// ---------------- bf16 MFMA GEMM: out[M,N] = A[M,K] * B[N,K]^T ----------------
template <int KDIM, int NDIM, int EPI>
__global__ __launch_bounds__(256, 2) void gemm_bf16(const unsigned short* __restrict__ Amat,
                                                    const unsigned short* __restrict__ Bmat,
                                                    float* __restrict__ outp,
                                                    unsigned short* __restrict__ q_out,
                                                    unsigned short* __restrict__ k_out,
                                                    unsigned short* __restrict__ v_out) {
    __shared__ __align__(16) unsigned short As[128 * 64];
    __shared__ __align__(16) unsigned short Bs[128 * 64];
    const int tid = threadIdx.x;
    const int l = tid & 63, wid = tid >> 6;
    const int g = l >> 4, c = l & 15;
    const int wr = wid >> 1, wc = wid & 1;
    const int row0 = blockIdx.y * 128, col0 = blockIdx.x * 128;

    f32x4 acc[4][4];
#pragma unroll
    for (int mi = 0; mi < 4; ++mi)
#pragma unroll
        for (int ni = 0; ni < 4; ++ni) acc[mi][ni] = (f32x4){0.f, 0.f, 0.f, 0.f};

    for (int k0 = 0; k0 < KDIM; k0 += 64) {
        bf16x8 ra[4], rb[4];
#pragma unroll
        for (int i = 0; i < 4; ++i) {
            int q = i * 256 + tid;
            int r = q >> 3, cb = (q & 7) * 16;
            ra[i] = *(const bf16x8*)((const char*)Amat + (size_t)(row0 + r) * (KDIM * 2) + k0 * 2 + cb);
            rb[i] = *(const bf16x8*)((const char*)Bmat + (size_t)(col0 + r) * (KDIM * 2) + k0 * 2 + cb);
        }
        __syncthreads();
#pragma unroll
        for (int i = 0; i < 4; ++i) {
            int q = i * 256 + tid;
            int r = q >> 3, cb = (q & 7) * 16;
            int sw = cb ^ ((r & 7) << 4);
            *(bf16x8*)((char*)As + r * 128 + sw) = ra[i];
            *(bf16x8*)((char*)Bs + r * 128 + sw) = rb[i];
        }
        __syncthreads();
#pragma unroll
        for (int kk = 0; kk < 2; ++kk) {
            bf16x8 afr[4], bfr[4];
#pragma unroll
            for (int mi = 0; mi < 4; ++mi) {
                int r = wr * 64 + mi * 16 + c;
                afr[mi] = *(const bf16x8*)((const char*)As + r * 128 + ((kk * 64 + g * 16) ^ ((r & 7) << 4)));
            }
#pragma unroll
            for (int ni = 0; ni < 4; ++ni) {
                int r = wc * 64 + ni * 16 + c;
                bfr[ni] = *(const bf16x8*)((const char*)Bs + r * 128 + ((kk * 64 + g * 16) ^ ((r & 7) << 4)));
            }
#pragma unroll
            for (int mi = 0; mi < 4; ++mi)
#pragma unroll
                for (int ni = 0; ni < 4; ++ni)
                    acc[mi][ni] = __builtin_amdgcn_mfma_f32_16x16x32_bf16(afr[mi], bfr[ni], acc[mi][ni], 0, 0, 0);
        }
    }
#pragma unroll
    for (int mi = 0; mi < 4; ++mi) {
#pragma unroll
        for (int ni = 0; ni < 4; ++ni) {
#pragma unroll
            for (int ii = 0; ii < 4; ++ii) {
                int m = row0 + wr * 64 + mi * 16 + g * 4 + ii;
                int n = col0 + wc * 64 + ni * 16 + c;
                float val = acc[mi][ni][ii];
                if (EPI == 0) {
                    unsigned short v = f2bf(val);
                    int b = m >> 10, ll = m & 1023;
                    int which = n >> 9, cc = n & 511;
                    int hh = cc >> 6, d = cc & 63;
                    int bh = b * 8 + hh;
                    if (which == 0)      q_out[((size_t)bh * L_ + ll) * D_ + d] = v;
                    else if (which == 1) k_out[((size_t)bh * L_ + ll) * D_ + d] = v;
                    else                 v_out[((size_t)bh * D_ + d) * L_ + ll] = v;
                } else {
                    outp[(size_t)m * NDIM + n] = val;
                }
            }
        }
    }
}

// ---------------- fused 3-branch attention: LDS-staged, 2-phase double buffer ----------------
// Block: 4 waves, each owns 16 q-rows of the same (bh, 64-q block); all share staged K/V tiles.
// Swapped QK^T (mfma(K,Q)) -> lane (c,g) holds S[q=c][k=4g+i]; PV uses k-permuted V reads so
// the P->A-fragment needs NO cross-lane traffic and NO LDS round-trip.
__global__ __launch_bounds__(256, 2) void attn_kernel(const unsigned short* __restrict__ Qb,
                                                      const unsigned short* __restrict__ Kb,
                                                      const unsigned short* __restrict__ Vtb,
                                                      const unsigned short* __restrict__ EI,
                                                      const float* __restrict__ beta,
                                                      unsigned short* __restrict__ hb) {
    // per buffer (32KB): K tile 8KB | V tile 8KB | E 4 waves x 4KB
    __shared__ __align__(16) char smem[2][32768];
    const int tid = threadIdx.x;
    const int w = tid >> 6, l = tid & 63;
    const int g = l >> 4, c = l & 15;
    const int bh = blockIdx.y, b = bh >> 3;
    const int q0 = blockIdx.x * 64 + w * 16;
    const int qt = blockIdx.x * 4 + w;

    const unsigned short* Qrow = Qb + ((size_t)bh * L_ + q0 + c) * D_;
    const bf16x8 qf0 = *(const bf16x8*)(Qrow + g * 8);
    const bf16x8 qf1 = *(const bf16x8*)(Qrow + 32 + g * 8);

    const unsigned short* Kbase = Kb + (size_t)bh * L_ * D_;   // row stride 64
    const unsigned short* Vbase = Vtb + (size_t)bh * D_ * L_;  // row stride 1024
    const unsigned short* Ebase = EI + ((size_t)(b * 64 + qt) * 64) * 512;

    f32x4 O[3][4];
#pragma unroll
    for (int j = 0; j < 3; ++j)
#pragma unroll
        for (int dc = 0; dc < 4; ++dc) O[j][dc] = (f32x4){0.f, 0.f, 0.f, 0.f};
    float lsum0 = 0.f, lsum1 = 0.f, lsum2 = 0.f;

    const int srow = l >> 3, sm = l & 7;       // staging row-within-8, chunk
    const int key = (c & 7) << 4;              // read-side swizzle key

    auto stage = [&](int t, char* base) {
        // K + V: wave w issues instrs 2w, 2w+1 of 8 (each covers 8 rows)
#pragma unroll
        for (int n = 0; n < 2; ++n) {
            int i = 2 * w + n;
            int row = i * 8 + srow;
            int sw = (sm ^ (row & 7)) * 8;     // pre-swizzled global source (rule #21)
            gload16(Kbase + (size_t)(t * 64 + row) * D_ + sw, base + i * 1024);
            gload16(Vbase + (size_t)row * L_ + t * 64 + sw, base + 8192 + i * 1024);
        }
        // E: per-wave 4 instrs, linear
#pragma unroll
        for (int ks = 0; ks < 4; ++ks)
            gload16(Ebase + (size_t)(t * 4 + ks) * 512 + l * 8, base + 16384 + w * 4096 + ks * 1024);
    };

    auto compute = [&](char* base) {
        char* Kl = base;
        char* Vl = base + 8192;
        char* El = base + 16384 + w * 4096;
        bf16x8 efr[4];
#pragma unroll
        for (int ks = 0; ks < 4; ++ks) efr[ks] = *(const bf16x8*)(El + ks * 1024 + l * 16);

        unsigned r[4][3][2];
#pragma unroll
        for (int st = 0; st < 4; ++st) {
            const char* kr = Kl + (st * 16 + c) * 128;
            bf16x8 ka = *(const bf16x8*)(kr + ((g * 16) ^ key));
            bf16x8 kb = *(const bf16x8*)(kr + ((64 + g * 16) ^ key));
            f32x4 s = (f32x4){0.f, 0.f, 0.f, 0.f};
            s = __builtin_amdgcn_mfma_f32_16x16x32_bf16(ka, qf0, s, 0, 0, 0);
            s = __builtin_amdgcn_mfma_f32_16x16x32_bf16(kb, qf1, s, 0, 0, 0);
            float p[3][4];
#pragma unroll
            for (int i = 0; i < 4; ++i) {
                float p0 = __expf(s[i] * 0.125f);
                float p1 = p0 * bf2f((unsigned short)efr[st][i]);
                float p2 = p0 * bf2f((unsigned short)efr[st][4 + i]);
                lsum0 += p0; lsum1 += p1; lsum2 += p2;
                p[0][i] = p0; p[1][i] = p1; p[2][i] = p2;
            }
#pragma unroll
            for (int j = 0; j < 3; ++j) {
                r[st][j][0] = __builtin_amdgcn_perm(__float_as_uint(p[j][1]), __float_as_uint(p[j][0]), 0x07060302u);
                r[st][j][1] = __builtin_amdgcn_perm(__float_as_uint(p[j][3]), __float_as_uint(p[j][2]), 0x07060302u);
            }
        }
#pragma unroll
        for (int kk = 0; kk < 2; ++kk) {
            bf16x8 af[3];
#pragma unroll
            for (int j = 0; j < 3; ++j) {
                union { unsigned u[4]; bf16x8 v; } t_;
                t_.u[0] = r[2 * kk][j][0];     t_.u[1] = r[2 * kk][j][1];
                t_.u[2] = r[2 * kk + 1][j][0]; t_.u[3] = r[2 * kk + 1][j][1];
                af[j] = t_.v;
            }
#pragma unroll
            for (int dc = 0; dc < 4; ++dc) {
                const char* vr = Vl + (dc * 16 + c) * 128;
                u32x2 vlo = *(const u32x2*)(vr + ((kk * 64 + g * 8) ^ key));
                u32x2 vhi = *(const u32x2*)(vr + ((kk * 64 + 32 + g * 8) ^ key));
                union { unsigned u[4]; bf16x8 v; } bv;
                bv.u[0] = vlo[0]; bv.u[1] = vlo[1]; bv.u[2] = vhi[0]; bv.u[3] = vhi[1];
#pragma unroll
                for (int j = 0; j < 3; ++j)
                    O[j][dc] = __builtin_amdgcn_mfma_f32_16x16x32_bf16(af[j], bv.v, O[j][dc], 0, 0, 0);
            }
        }
    };

    stage(0, smem[0]);
    __syncthreads();
#pragma unroll 1
    for (int t = 0; t < 16; t += 2) {
        stage(t + 1, smem[1]);
        compute(smem[0]);
        __syncthreads();
        if (t + 2 < 16) stage(t + 2, smem[0]);
        compute(smem[1]);
        __syncthreads();
    }

    // reduce lsum over g-groups (k partitioned across g)
    lsum0 += __shfl_xor(lsum0, 16); lsum0 += __shfl_xor(lsum0, 32);
    lsum1 += __shfl_xor(lsum1, 16); lsum1 += __shfl_xor(lsum1, 32);
    lsum2 += __shfl_xor(lsum2, 16); lsum2 += __shfl_xor(lsum2, 32);

    float b0 = beta[0], b1 = beta[1], b2 = beta[2];
    float bm = fmaxf(b0, fmaxf(b1, b2));
    float e0 = __expf(b0 - bm), e1 = __expf(b1 - bm), e2 = __expf(b2 - bm);
    float inv = 1.0f / (e0 + e1 + e2);
    float i0 = e0 * inv / lsum0, i1 = e1 * inv / lsum1, i2 = e2 * inv / lsum2;

    // lane (c,g) holds O rows q=4g+ii, cols d=dc*16+c; fetch per-row 1/lsum from lane q
    float iq0[4], iq1[4], iq2[4];
#pragma unroll
    for (int ii = 0; ii < 4; ++ii) {
        iq0[ii] = __shfl(i0, g * 4 + ii);
        iq1[ii] = __shfl(i1, g * 4 + ii);
        iq2[ii] = __shfl(i2, g * 4 + ii);
    }
    const int hcol = (bh & 7) * 64;
#pragma unroll
    for (int dc = 0; dc < 4; ++dc) {
#pragma unroll
        for (int ii = 0; ii < 4; ++ii) {
            float h = iq0[ii] * O[0][dc][ii] + iq1[ii] * O[1][dc][ii] + iq2[ii] * O[2][dc][ii];
            int qrow = q0 + g * 4 + ii;
            hb[((size_t)(b << 10) + qrow) * C_ + hcol + dc * 16 + c] = f2bf(h);
        }
    }
}

extern "C" void kernel_launch(void* const* d_in, const int* in_sizes, int n_in,
                              void* d_out, int out_size, void* d_ws, size_t ws_size,
                              hipStream_t stream) {
    const float* x          = (const float*)d_in[0];
    const float* adj        = (const float*)d_in[1];
    const float* wqkv       = (const float*)d_in[2];
    const float* wproj      = (const float*)d_in[3];
    const float* bias_scale = (const float*)d_in[4];
    const float* beta       = (const float*)d_in[5];
    float* out = (float*)d_out;

    char* ws = (char*)d_ws;
    size_t off = 0;
    auto alloc = [&](size_t bytes) {
        void* p = ws + off;
        off += (bytes + 255) & ~(size_t)255;
        return p;
    };
    unsigned short* xb     = (unsigned short*)alloc((size_t)M_ * C_ * 2);
    unsigned short* wqkvb  = (unsigned short*)alloc((size_t)3 * C_ * C_ * 2);
    unsigned short* wprojb = (unsigned short*)alloc((size_t)C_ * C_ * 2);
    unsigned short* Qb     = (unsigned short*)alloc((size_t)BH_ * L_ * D_ * 2);
    unsigned short* Kb     = (unsigned short*)alloc((size_t)BH_ * L_ * D_ * 2);
    unsigned short* Vtb    = (unsigned short*)alloc((size_t)BH_ * D_ * L_ * 2);
    // EI holds ef AND eb per (b,q,k): B*L*L*2 bf16 elements = B*L*L*4 BYTES.
    // (Round-4 bug: allocated B*L*L*2 bytes -> prep_e overflowed into hb.)
    unsigned short* EI     = (unsigned short*)alloc((size_t)B_ * L_ * L_ * 4);
    unsigned short* hb     = (unsigned short*)alloc((size_t)M_ * C_ * 2);

    {
        int n4 = M_ * C_ / 4;
        cvt_bf16<<<(n4 + 255) / 256, 256, 0, stream>>>(x, xb, n4);
    }
    {
        int n4 = 3 * C_ * C_ / 4;
        cvt_bf16<<<(n4 + 255) / 256, 256, 0, stream>>>(wqkv, wqkvb, n4);
    }
    {
        int n4 = C_ * C_ / 4;
        cvt_bf16<<<(n4 + 255) / 256, 256, 0, stream>>>(wproj, wprojb, n4);
    }
    prep_e<<<dim3(L_ / 64, L_ / 64, B_), 256, 0, stream>>>(adj, bias_scale, EI);
    gemm_bf16<512, 1536, 0><<<dim3(1536 / 128, M_ / 128), 256, 0, stream>>>(xb, wqkvb, nullptr, Qb, Kb, Vtb);
    attn_kernel<<<dim3(L_ / 64, BH_), 256, 0, stream>>>(Qb, Kb, Vtb, EI, beta, hb);
    gemm_bf16<512, 512, 1><<<dim3(512 / 128, M_ / 128), 256, 0, stream>>>(hb, wprojb, out, nullptr, nullptr, nullptr);
}

// Round 6
// 71.842 us; speedup vs baseline: 1.8367x; 1.1435x over previous
//
#include <hip/hip_runtime.h>
#include <hip/hip_bf16.h>
#include <stdint.h>

#define B_  4
#define L_  1024
#define C_  512
#define H_  8
#define D_  64
#define BH_ 32
#define M_  4096

typedef short  bf16x8 __attribute__((ext_vector_type(8)));
typedef float  f32x4  __attribute__((ext_vector_type(4)));
typedef unsigned short u16x8 __attribute__((ext_vector_type(8)));
typedef unsigned int   u32x2 __attribute__((ext_vector_type(2)));

__device__ __forceinline__ unsigned short f2bf(float f) {
    union { float f; uint32_t u; } v; v.f = f;
    uint32_t u = v.u;
    return (unsigned short)((u + 0x7fffu + ((u >> 16) & 1u)) >> 16);
}
__device__ __forceinline__ float bf2f(unsigned short s) {
    union { uint32_t u; float f; } v; v.u = ((uint32_t)s) << 16;
    return v.f;
}

// async global->LDS, 16B per lane; LDS dest = wave-uniform base + lane*16
__device__ __forceinline__ void gload16(const void* g, void* s) {
    __builtin_amdgcn_global_load_lds((const __attribute__((address_space(1))) void*)g,
                                     (__attribute__((address_space(3))) void*)s, 16, 0, 0);
}

// ---------------- fused f32 -> bf16 convert for x, W_qkv, W_proj ----------------
#define NX4   (M_ * C_ / 4)            // 524288
#define NWQ4  (3 * C_ * C_ / 4)        // 196608
#define NWP4  (C_ * C_ / 4)            // 65536
__global__ void cvt_all(const float* __restrict__ x, const float* __restrict__ wq,
                        const float* __restrict__ wp,
                        unsigned short* __restrict__ xb, unsigned short* __restrict__ wqb,
                        unsigned short* __restrict__ wpb) {
    int i = blockIdx.x * 256 + threadIdx.x;
    const float* src; unsigned short* dst; int o;
    if (i < NX4) { src = x; dst = xb; o = i; }
    else if (i < NX4 + NWQ4) { src = wq; dst = wqb; o = i - NX4; }
    else if (i < NX4 + NWQ4 + NWP4) { src = wp; dst = wpb; o = i - NX4 - NWQ4; }
    else return;
    float4 v = ((const float4*)src)[o];
    ushort4 r;
    r.x = f2bf(v.x); r.y = f2bf(v.y); r.z = f2bf(v.z); r.w = f2bf(v.w);
    ((ushort4*)dst)[o] = r;
}

// ---------------- precompute E = exp(bias) in swapped-QK fragment layout ----------------
// EI layout: [b][q16(64)][k16(64)][lane(64)][ef x4 | eb x4] bf16 (16B per lane).
// lane l=(c,g), elem i: q = q16*16 + c, k = k16*16 + 4g + i.
__global__ __launch_bounds__(256) void prep_e(const float* __restrict__ adj,
                                              const float* __restrict__ bias_scale,
                                              unsigned short* __restrict__ EI) {
    __shared__ float Tr[64][65];
    const int b = blockIdx.z, q0 = blockIdx.y * 64, k0 = blockIdx.x * 64;
    const float* adjb = adj + (size_t)b * L_ * L_;
    const int tid = threadIdx.x;
#pragma unroll
    for (int i = 0; i < 4; ++i) {
        int idx = i * 256 + tid;                 // 0..1023
        int rk = idx >> 4, c4 = (idx & 15) * 4;  // row (k), col4 (q)
        float4 v = *(const float4*)(adjb + (size_t)(k0 + rk) * L_ + q0 + c4);
        Tr[rk][c4 + 0] = v.x; Tr[rk][c4 + 1] = v.y; Tr[rk][c4 + 2] = v.z; Tr[rk][c4 + 3] = v.w;
    }
    __syncthreads();
    const float bs0 = bias_scale[0], bs1 = bias_scale[1];
    const int w = tid >> 6, l = tid & 63, g = l >> 4, c = l & 15;
#pragma unroll
    for (int qs = 0; qs < 4; ++qs) {
        int ql = qs * 16 + c, qg = q0 + ql;
        int klb = w * 16 + g * 4;
        float4 af4 = *(const float4*)(adjb + (size_t)qg * L_ + k0 + klb);
        unsigned short ef[4], eb[4];
        const float afv[4] = {af4.x, af4.y, af4.z, af4.w};
#pragma unroll
        for (int i = 0; i < 4; ++i) {
            int kg = k0 + klb + i;
            bool z = (qg == 0) || (kg == 0);
            ef[i] = f2bf(z ? 1.0f : __expf(bs0 * afv[i]));
            eb[i] = f2bf(z ? 1.0f : __expf(bs1 * Tr[klb + i][ql]));
        }
        size_t o = (((size_t)b * 64 + (blockIdx.y * 4 + qs)) * 64 + (blockIdx.x * 4 + w)) * 512 + (size_t)l * 8;
        u16x8 o8 = {ef[0], ef[1], ef[2], ef[3], eb[0], eb[1], eb[2], eb[3]};
        *(u16x8*)(EI + o) = o8;
    }
}

// ---------------- bf16 MFMA GEMM: out[M,N] = A[M,K] * B[N,K]^T ----------------
// Tile BM x BN, 4 waves (2x2). EPI 0: scatter qkv -> Qb/Kb/Vt. EPI 1: f32 store.
template <int BM, int BN, int KDIM, int EPI, int NDIM>
__global__ __launch_bounds__(256, 4) void gemm_bf16(const unsigned short* __restrict__ Amat,
                                                    const unsigned short* __restrict__ Bmat,
                                                    float* __restrict__ outp,
                                                    unsigned short* __restrict__ q_out,
                                                    unsigned short* __restrict__ k_out,
                                                    unsigned short* __restrict__ v_out) {
    constexpr int NA = BM / 32, NB = BN / 32;   // 16B staging chunks per thread
    constexpr int MI = BM / 32, NI = BN / 32;   // acc tiles per wave (RM/16, RN/16)
    __shared__ __align__(16) unsigned short As[BM * 64];
    __shared__ __align__(16) unsigned short Bs[BN * 64];
    const int tid = threadIdx.x;
    const int l = tid & 63, wid = tid >> 6;
    const int g = l >> 4, c = l & 15;
    const int wr = wid >> 1, wc = wid & 1;
    const int row0 = blockIdx.y * BM, col0 = blockIdx.x * BN;

    f32x4 acc[MI][NI];
#pragma unroll
    for (int mi = 0; mi < MI; ++mi)
#pragma unroll
        for (int ni = 0; ni < NI; ++ni) acc[mi][ni] = (f32x4){0.f, 0.f, 0.f, 0.f};

    for (int k0 = 0; k0 < KDIM; k0 += 64) {
        bf16x8 ra[NA], rb[NB];
#pragma unroll
        for (int i = 0; i < NA; ++i) {
            int q = i * 256 + tid;
            int r = q >> 3, cb = (q & 7) * 16;
            ra[i] = *(const bf16x8*)((const char*)Amat + (size_t)(row0 + r) * (KDIM * 2) + k0 * 2 + cb);
        }
#pragma unroll
        for (int i = 0; i < NB; ++i) {
            int q = i * 256 + tid;
            int r = q >> 3, cb = (q & 7) * 16;
            rb[i] = *(const bf16x8*)((const char*)Bmat + (size_t)(col0 + r) * (KDIM * 2) + k0 * 2 + cb);
        }
        __syncthreads();
#pragma unroll
        for (int i = 0; i < NA; ++i) {
            int q = i * 256 + tid;
            int r = q >> 3, cb = (q & 7) * 16;
            *(bf16x8*)((char*)As + r * 128 + (cb ^ ((r & 7) << 4))) = ra[i];
        }
#pragma unroll
        for (int i = 0; i < NB; ++i) {
            int q = i * 256 + tid;
            int r = q >> 3, cb = (q & 7) * 16;
            *(bf16x8*)((char*)Bs + r * 128 + (cb ^ ((r & 7) << 4))) = rb[i];
        }
        __syncthreads();
#pragma unroll
        for (int kk = 0; kk < 2; ++kk) {
            bf16x8 afr[MI], bfr[NI];
#pragma unroll
            for (int mi = 0; mi < MI; ++mi) {
                int r = wr * (BM / 2) + mi * 16 + c;
                afr[mi] = *(const bf16x8*)((const char*)As + r * 128 + ((kk * 64 + g * 16) ^ ((r & 7) << 4)));
            }
#pragma unroll
            for (int ni = 0; ni < NI; ++ni) {
                int r = wc * (BN / 2) + ni * 16 + c;
                bfr[ni] = *(const bf16x8*)((const char*)Bs + r * 128 + ((kk * 64 + g * 16) ^ ((r & 7) << 4)));
            }
#pragma unroll
            for (int mi = 0; mi < MI; ++mi)
#pragma unroll
                for (int ni = 0; ni < NI; ++ni)
                    acc[mi][ni] = __builtin_amdgcn_mfma_f32_16x16x32_bf16(afr[mi], bfr[ni], acc[mi][ni], 0, 0, 0);
        }
    }
#pragma unroll
    for (int mi = 0; mi < MI; ++mi) {
#pragma unroll
        for (int ni = 0; ni < NI; ++ni) {
#pragma unroll
            for (int ii = 0; ii < 4; ++ii) {
                int m = row0 + wr * (BM / 2) + mi * 16 + g * 4 + ii;
                int n = col0 + wc * (BN / 2) + ni * 16 + c;
                float val = acc[mi][ni][ii];
                if (EPI == 0) {
                    unsigned short v = f2bf(val);
                    int b = m >> 10, ll = m & 1023;
                    int which = n >> 9, cc = n & 511;
                    int hh = cc >> 6, d = cc & 63;
                    int bh = b * 8 + hh;
                    if (which == 0)      q_out[((size_t)bh * L_ + ll) * D_ + d] = v;
                    else if (which == 1) k_out[((size_t)bh * L_ + ll) * D_ + d] = v;
                    else                 v_out[((size_t)bh * D_ + d) * L_ + ll] = v;
                } else {
                    outp[(size_t)m * NDIM + n] = val;
                }
            }
        }
    }
}

// ---------------- fused 3-branch attention: LDS-staged K/V, E in registers ----------------
// Swapped QK^T (mfma(K,Q)) -> lane (c,g) holds S[q=c][k=4g+i]; P feeds PV A-fragment
// in-register (perm pack); V read k-permuted to match. K/V double-buffered via
// global_load_lds; E prefetched into registers (2-deep).
struct EReg { bf16x8 e[4]; };

__global__ __launch_bounds__(256, 2) void attn_kernel(const unsigned short* __restrict__ Qb,
                                                      const unsigned short* __restrict__ Kb,
                                                      const unsigned short* __restrict__ Vtb,
                                                      const unsigned short* __restrict__ EI,
                                                      const float* __restrict__ beta,
                                                      unsigned short* __restrict__ hb) {
    // per buffer (16KB): K tile 8KB | V tile 8KB
    __shared__ __align__(16) char smem[2][16384];
    const int tid = threadIdx.x;
    const int w = tid >> 6, l = tid & 63;
    const int g = l >> 4, c = l & 15;

    // XCD-grouping swizzle: the 8 head-blocks sharing one (b, q64) EI slice land on
    // the same XCD (consecutive dispatch positions stride-8 apart -> same p%8).
    const int p = blockIdx.x;                 // 0..511
    const int s = (p & 7) + 8 * (p >> 6);     // (b, qb) index 0..63
    const int h = (p >> 3) & 7;
    const int b = s >> 4, qb = s & 15;
    const int bh = b * 8 + h;
    const int q0 = qb * 64 + w * 16;
    const int qt = qb * 4 + w;

    const unsigned short* Qrow = Qb + ((size_t)bh * L_ + q0 + c) * D_;
    const bf16x8 qf0 = *(const bf16x8*)(Qrow + g * 8);
    const bf16x8 qf1 = *(const bf16x8*)(Qrow + 32 + g * 8);

    const unsigned short* Kbase = Kb + (size_t)bh * L_ * D_;   // row stride 64
    const unsigned short* Vbase = Vtb + (size_t)bh * D_ * L_;  // row stride 1024
    const unsigned short* Ebase = EI + ((size_t)(b * 64 + qt) * 64) * 512;

    f32x4 O[3][4];
#pragma unroll
    for (int j = 0; j < 3; ++j)
#pragma unroll
        for (int dc = 0; dc < 4; ++dc) O[j][dc] = (f32x4){0.f, 0.f, 0.f, 0.f};
    float lsum0 = 0.f, lsum1 = 0.f, lsum2 = 0.f;

    const int srow = l >> 3, sm = l & 7;       // staging row-within-8, chunk
    const int key = (c & 7) << 4;              // read-side swizzle key

    auto stage = [&](int t, char* base) {
#pragma unroll
        for (int n = 0; n < 2; ++n) {
            int i = 2 * w + n;
            int row = i * 8 + srow;
            int sw = (sm ^ (row & 7)) * 8;     // pre-swizzled global source
            gload16(Kbase + (size_t)(t * 64 + row) * D_ + sw, base + i * 1024);
            gload16(Vbase + (size_t)row * L_ + t * 64 + sw, base + 8192 + i * 1024);
        }
    };
    auto eload = [&](EReg& X, int t) {
#pragma unroll
        for (int ks = 0; ks < 4; ++ks)
            X.e[ks] = *(const bf16x8*)(Ebase + (size_t)(t * 4 + ks) * 512 + l * 8);
    };

    auto compute = [&](const char* base, const EReg& E) {
        const char* Kl = base;
        const char* Vl = base + 8192;
        unsigned r[4][3][2];
#pragma unroll
        for (int st = 0; st < 4; ++st) {
            const char* kr = Kl + (st * 16 + c) * 128;
            bf16x8 ka = *(const bf16x8*)(kr + ((g * 16) ^ key));
            bf16x8 kb = *(const bf16x8*)(kr + ((64 + g * 16) ^ key));
            f32x4 sacc = (f32x4){0.f, 0.f, 0.f, 0.f};
            sacc = __builtin_amdgcn_mfma_f32_16x16x32_bf16(ka, qf0, sacc, 0, 0, 0);
            sacc = __builtin_amdgcn_mfma_f32_16x16x32_bf16(kb, qf1, sacc, 0, 0, 0);
            float pv[3][4];
#pragma unroll
            for (int i = 0; i < 4; ++i) {
                float p0 = __expf(sacc[i] * 0.125f);
                float p1 = p0 * bf2f((unsigned short)E.e[st][i]);
                float p2 = p0 * bf2f((unsigned short)E.e[st][4 + i]);
                lsum0 += p0; lsum1 += p1; lsum2 += p2;
                pv[0][i] = p0; pv[1][i] = p1; pv[2][i] = p2;
            }
#pragma unroll
            for (int j = 0; j < 3; ++j) {
                r[st][j][0] = __builtin_amdgcn_perm(__float_as_uint(pv[j][1]), __float_as_uint(pv[j][0]), 0x07060302u);
                r[st][j][1] = __builtin_amdgcn_perm(__float_as_uint(pv[j][3]), __float_as_uint(pv[j][2]), 0x07060302u);
            }
        }
#pragma unroll
        for (int kk = 0; kk < 2; ++kk) {
            bf16x8 af[3];
#pragma unroll
            for (int j = 0; j < 3; ++j) {
                union { unsigned u[4]; bf16x8 v; } t_;
                t_.u[0] = r[2 * kk][j][0];     t_.u[1] = r[2 * kk][j][1];
                t_.u[2] = r[2 * kk + 1][j][0]; t_.u[3] = r[2 * kk + 1][j][1];
                af[j] = t_.v;
            }
#pragma unroll
            for (int dc = 0; dc < 4; ++dc) {
                const char* vr = Vl + (dc * 16 + c) * 128;
                u32x2 vlo = *(const u32x2*)(vr + ((kk * 64 + g * 8) ^ key));
                u32x2 vhi = *(const u32x2*)(vr + ((kk * 64 + 32 + g * 8) ^ key));
                union { unsigned u[4]; bf16x8 v; } bv;
                bv.u[0] = vlo[0]; bv.u[1] = vlo[1]; bv.u[2] = vhi[0]; bv.u[3] = vhi[1];
#pragma unroll
                for (int j = 0; j < 3; ++j)
                    O[j][dc] = __builtin_amdgcn_mfma_f32_16x16x32_bf16(af[j], bv.v, O[j][dc], 0, 0, 0);
            }
        }
    };

    EReg E0, E1;
    stage(0, smem[0]);
    eload(E0, 0);
    __syncthreads();
#pragma unroll 1
    for (int t = 0; t < 16; t += 2) {
        stage(t + 1, smem[1]);
        eload(E1, t + 1);
        compute(smem[0], E0);
        __syncthreads();
        if (t + 2 < 16) { stage(t + 2, smem[0]); eload(E0, t + 2); }
        compute(smem[1], E1);
        __syncthreads();
    }

    // reduce lsum over g-groups (k partitioned across g)
    lsum0 += __shfl_xor(lsum0, 16); lsum0 += __shfl_xor(lsum0, 32);
    lsum1 += __shfl_xor(lsum1, 16); lsum1 += __shfl_xor(lsum1, 32);
    lsum2 += __shfl_xor(lsum2, 16); lsum2 += __shfl_xor(lsum2, 32);

    float b0 = beta[0], b1 = beta[1], b2 = beta[2];
    float bm = fmaxf(b0, fmaxf(b1, b2));
    float e0 = __expf(b0 - bm), e1 = __expf(b1 - bm), e2 = __expf(b2 - bm);
    float inv = 1.0f / (e0 + e1 + e2);
    float i0 = e0 * inv / lsum0, i1 = e1 * inv / lsum1, i2 = e2 * inv / lsum2;

    // lane (c,g) holds O rows q=4g+ii, cols d=dc*16+c; fetch per-row 1/lsum from lane q
    float iq0[4], iq1[4], iq2[4];
#pragma unroll
    for (int ii = 0; ii < 4; ++ii) {
        iq0[ii] = __shfl(i0, g * 4 + ii);
        iq1[ii] = __shfl(i1, g * 4 + ii);
        iq2[ii] = __shfl(i2, g * 4 + ii);
    }
    const int hcol = (bh & 7) * 64;
#pragma unroll
    for (int dc = 0; dc < 4; ++dc) {
#pragma unroll
        for (int ii = 0; ii < 4; ++ii) {
            float hv = iq0[ii] * O[0][dc][ii] + iq1[ii] * O[1][dc][ii] + iq2[ii] * O[2][dc][ii];
            int qrow = q0 + g * 4 + ii;
            hb[((size_t)(b << 10) + qrow) * C_ + hcol + dc * 16 + c] = f2bf(hv);
        }
    }
}

extern "C" void kernel_launch(void* const* d_in, const int* in_sizes, int n_in,
                              void* d_out, int out_size, void* d_ws, size_t ws_size,
                              hipStream_t stream) {
    const float* x          = (const float*)d_in[0];
    const float* adj        = (const float*)d_in[1];
    const float* wqkv       = (const float*)d_in[2];
    const float* wproj      = (const float*)d_in[3];
    const float* bias_scale = (const float*)d_in[4];
    const float* beta       = (const float*)d_in[5];
    float* out = (float*)d_out;

    char* ws = (char*)d_ws;
    size_t off = 0;
    auto alloc = [&](size_t bytes) {
        void* p = ws + off;
        off += (bytes + 255) & ~(size_t)255;
        return p;
    };
    unsigned short* xb     = (unsigned short*)alloc((size_t)M_ * C_ * 2);
    unsigned short* wqkvb  = (unsigned short*)alloc((size_t)3 * C_ * C_ * 2);
    unsigned short* wprojb = (unsigned short*)alloc((size_t)C_ * C_ * 2);
    unsigned short* Qb     = (unsigned short*)alloc((size_t)BH_ * L_ * D_ * 2);
    unsigned short* Kb     = (unsigned short*)alloc((size_t)BH_ * L_ * D_ * 2);
    unsigned short* Vtb    = (unsigned short*)alloc((size_t)BH_ * D_ * L_ * 2);
    unsigned short* EI     = (unsigned short*)alloc((size_t)B_ * L_ * L_ * 4);  // ef+eb: B*L*L*2 bf16
    unsigned short* hb     = (unsigned short*)alloc((size_t)M_ * C_ * 2);

    cvt_all<<<(NX4 + NWQ4 + NWP4 + 255) / 256, 256, 0, stream>>>(x, wqkv, wproj, xb, wqkvb, wprojb);
    prep_e<<<dim3(L_ / 64, L_ / 64, B_), 256, 0, stream>>>(adj, bias_scale, EI);
    gemm_bf16<64, 128, 512, 0, 0><<<dim3(1536 / 128, M_ / 64), 256, 0, stream>>>(xb, wqkvb, nullptr, Qb, Kb, Vtb);
    attn_kernel<<<dim3(512), 256, 0, stream>>>(Qb, Kb, Vtb, EI, beta, hb);
    gemm_bf16<64, 64, 512, 1, 512><<<dim3(512 / 64, M_ / 64), 256, 0, stream>>>(hb, wprojb, out, nullptr, nullptr, nullptr);
}